// Round 16
// baseline (214.706 us; speedup 1.0000x reference)
//
#include <hip/hip_runtime.h>
#include <math.h>
#include <stdint.h>

// Problem constants (static per reference)
#define BB 8
#define NN 384
#define FF 64
#define TT 192
#define NSRC 383          // T + TAU - 1
#define NSINK 192
#define SS 5
#define NEDGE 441600      // B * 55200
#define BN (BB * NN)      // 3072
#define TILE_E 128        // edges per block (2 waves x 64, lane <-> edge)
#define NBLKE (NEDGE / TILE_E)    // 3450 exactly
#define OUTV ((BB * NN * NN) / 4) // 294912 float4 to zero

typedef _Float16 half8 __attribute__((ext_vector_type(8)));
typedef __fp16 fp16x2 __attribute__((ext_vector_type(2)));
typedef float floatx4 __attribute__((ext_vector_type(4)));

// 2-limb f16 split (prep side, RNE): x ~= h + l/512
static __device__ __forceinline__ void split_f16(float x, uint16_t& h, uint16_t& l) {
  const _Float16 hh = (_Float16)x;
  const float hb = (float)hh;
  const _Float16 ll = (_Float16)((x - hb) * 512.f);
  h = __builtin_bit_cast(uint16_t, hh);
  l = __builtin_bit_cast(uint16_t, ll);
}

// pair split via v_cvt_pkrtz (RTZ hi; residual captured exactly by the lo limb)
static __device__ __forceinline__ void split_pair(float x0, float x1,
                                                  uint32_t& hi, uint32_t& lo) {
  const fp16x2 h = __builtin_amdgcn_cvt_pkrtz(x0, x1);
  const float hb0 = (float)h.x, hb1 = (float)h.y;
  const fp16x2 l = __builtin_amdgcn_cvt_pkrtz((x0 - hb0) * 512.f, (x1 - hb1) * 512.f);
  hi = __builtin_bit_cast(uint32_t, h);
  lo = __builtin_bit_cast(uint32_t, l);
}

// ---------------- prep: node projections + weight folding + W f16-limb frags ----------------
// W frag slab (A-operand layout, per limb): ushort idx = (((jt*2+kc)*4+q)*16 + m)*8 + jj
//   <-> W[k = 32*kc + 8*q + jj][j = 16*jt + m]   (g1-folded weight)
__global__ __launch_bounds__(64) void prep_all(
    const float* __restrict__ nodes, const float* __restrict__ w1,
    const float* __restrict__ b1,
    const float* __restrict__ w2, const float* __restrict__ b2,
    const float* __restrict__ g1, const float* __restrict__ be1,
    const float* __restrict__ g2, const float* __restrict__ be2,
    const float* __restrict__ w3, const float* __restrict__ b3,
    float* __restrict__ A, float* __restrict__ Bv,
    unsigned short* __restrict__ Whg, unsigned short* __restrict__ Wlg,
    float* __restrict__ cb, float* __restrict__ gw, float* __restrict__ cwsgw) {
  const int blk = blockIdx.x;
  const int k = threadIdx.x;
  if (blk < BN / 4) {
    const int bn0 = blk * 4;
    __shared__ float nd[4][FF];
#pragma unroll
    for (int i = 0; i < 4; ++i) nd[i][k] = nodes[(bn0 + i) * FF + k];
    __syncthreads();
    const float bk = b1[k];
    float a0 = bk, a1 = bk, a2 = bk, a3 = bk;
    float q0 = 0.f, q1 = 0.f, q2 = 0.f, q3 = 0.f;
#pragma unroll 8
    for (int f = 0; f < FF; ++f) {
      const float wt = w1[f * FF + k];
      const float wb = w1[(FF + f) * FF + k];
      const float n0 = nd[0][f], n1 = nd[1][f], n2 = nd[2][f], n3 = nd[3][f];
      a0 = fmaf(n0, wt, a0); a1 = fmaf(n1, wt, a1);
      a2 = fmaf(n2, wt, a2); a3 = fmaf(n3, wt, a3);
      q0 = fmaf(n0, wb, q0); q1 = fmaf(n1, wb, q1);
      q2 = fmaf(n2, wb, q2); q3 = fmaf(n3, wb, q3);
    }
    A[(bn0 + 0) * FF + k] = a0;  Bv[(bn0 + 0) * FF + k] = q0;
    A[(bn0 + 1) * FF + k] = a1;  Bv[(bn0 + 1) * FF + k] = q1;
    A[(bn0 + 2) * FF + k] = a2;  Bv[(bn0 + 2) * FF + k] = q2;
    A[(bn0 + 3) * FF + k] = a3;  Bv[(bn0 + 3) * FF + k] = q3;
  } else {
    const int j = k;
    const int jt = j >> 4, m = j & 15;
    float cbj = b2[j];
    for (int kk = 0; kk < FF; ++kk) {
      const float wraw = w2[kk * FF + j];
      const float w = g1[kk] * wraw;
      cbj = fmaf(be1[kk], wraw, cbj);
      uint16_t hu, lu;
      split_f16(w, hu, lu);
      const int kc = kk >> 5, qq = (kk >> 3) & 3, jj = kk & 7;
      const int idx = (((jt * 2 + kc) * 4 + qq) * 16 + m) * 8 + jj;
      Whg[idx] = hu;
      Wlg[idx] = lu;
    }
    cb[j] = cbj;
    const float gwj = g2[j] * w3[j];
    gw[j] = gwj;
    __shared__ float sA[FF], sB[FF];
    sA[j] = gwj;
    sB[j] = be2[j] * w3[j];
    __syncthreads();
    if (j == 0) {
      float a = 0.f, bq = 0.f;
      for (int i = 0; i < FF; ++i) { a += sA[i]; bq += sB[i]; }
      cwsgw[0] = b3[0] + bq;
      cwsgw[1] = a;
    }
  }
}

// ---------------- main: MFMA edge MLP; wave-autonomous, centered-x limbs ----------------
// 128 thr = 2 waves, wave owns 64 edges (local edge = lane).
// X limbs store (x - mu): LN1 centering folded into the GEMM operand, rstd in epilogue.
// mfma_f32_16x16x32_f16: A[m=lane&15][k=8*(lane>>4)+jj]; D col=lane&15, row=4*(lane>>4)+reg.
__global__ __launch_bounds__(128, 3) void edge_mlp(
    const float* __restrict__ A, const float* __restrict__ Bv,
    const unsigned short* __restrict__ Whg, const unsigned short* __restrict__ Wlg,
    const float* __restrict__ cbg, const float* __restrict__ gwg,
    const float* __restrict__ cwsgw,
    const int* __restrict__ bidx, const int* __restrict__ ridx,
    const int* __restrict__ cidx, float* __restrict__ L,
    float4* __restrict__ outv) {
  __shared__ __align__(16) unsigned short XHs[8192];   // 16 KB  X hi frags (2 waves)
  __shared__ __align__(16) unsigned short XLs[8192];   // 16 KB  X lo frags

  const int tid = threadIdx.x;       // 0..127
  const int wave = tid >> 6;
  const int lane = tid & 63;
  const int q4 = lane >> 4;          // quad
  const int c15 = lane & 15;

  // fused zeroing of the output grid (3450*128 = 441600 >= OUTV)
  const int gtid = blockIdx.x * 128 + tid;
  if (gtid < OUTV) outv[gtid] = make_float4(0.f, 0.f, 0.f, 0.f);

  // ---- phase 1: lane <-> edge; pass A = stats, pass B = reload+center+split ----
  const int ge = blockIdx.x * TILE_E + tid;
  const int b = bidx[ge], r = ridx[ge], c = cidx[ge];
  const int et_own = lane >> 4, n_own = lane & 15;
  const float4* pa = (const float4*)(A + (b * NN + r) * FF);
  const float4* pb = (const float4*)(Bv + (b * NN + c) * FF);
  float mu, rstd;
  {
    float s = 0.f, q = 0.f;
#pragma unroll
    for (int i = 0; i < 16; ++i) {
      const float4 av = pa[i];
      const float4 bv = pb[i];
      const float x0 = fmaxf(av.x + bv.x, 0.f);
      const float x1 = fmaxf(av.y + bv.y, 0.f);
      const float x2 = fmaxf(av.z + bv.z, 0.f);
      const float x3 = fmaxf(av.w + bv.w, 0.f);
      s += x0 + x1 + x2 + x3;
      q = fmaf(x0, x0, q); q = fmaf(x1, x1, q);
      q = fmaf(x2, x2, q); q = fmaf(x3, x3, q);
    }
    mu = s * (1.f / FF);
    rstd = 1.f / sqrtf(q * (1.f / FF) - mu * mu + 1e-5f);
  }
  {
    unsigned short* dh = &XHs[wave * 4096 + n_own * 8];
    unsigned short* dl = &XLs[wave * 4096 + n_own * 8];
#pragma unroll
    for (int g = 0; g < 8; ++g) {     // g -> k in [8g, 8g+8): kc=g>>2, q=g&3  (L1-hot reload)
      const float4 av0 = pa[2 * g], av1 = pa[2 * g + 1];
      const float4 bv0 = pb[2 * g], bv1 = pb[2 * g + 1];
      const float x0 = fmaxf(av0.x + bv0.x, 0.f) - mu;
      const float x1 = fmaxf(av0.y + bv0.y, 0.f) - mu;
      const float x2 = fmaxf(av0.z + bv0.z, 0.f) - mu;
      const float x3 = fmaxf(av0.w + bv0.w, 0.f) - mu;
      const float x4 = fmaxf(av1.x + bv1.x, 0.f) - mu;
      const float x5 = fmaxf(av1.y + bv1.y, 0.f) - mu;
      const float x6 = fmaxf(av1.z + bv1.z, 0.f) - mu;
      const float x7 = fmaxf(av1.w + bv1.w, 0.f) - mu;
      int4 hi4, lo4;
      split_pair(x0, x1, *(uint32_t*)&hi4.x, *(uint32_t*)&lo4.x);
      split_pair(x2, x3, *(uint32_t*)&hi4.y, *(uint32_t*)&lo4.y);
      split_pair(x4, x5, *(uint32_t*)&hi4.z, *(uint32_t*)&lo4.z);
      split_pair(x6, x7, *(uint32_t*)&hi4.w, *(uint32_t*)&lo4.w);
      const int choff = ((et_own * 2 + (g >> 2)) * 4 + (g & 3)) * 128;
      *(int4*)(dh + choff) = hi4;
      *(int4*)(dl + choff) = lo4;
    }
  }

  // ---- hoist W frags into registers (16 KB table, L1-hot across blocks) ----
  half8 whr[4][2], wlr[4][2];
#pragma unroll
  for (int jt = 0; jt < 4; ++jt)
#pragma unroll
    for (int kc = 0; kc < 2; ++kc) {
      const int woff = ((jt * 2 + kc) * 4 + q4) * 128 + c15 * 8;
      whr[jt][kc] = *(const half8*)&Whg[woff];
      wlr[jt][kc] = *(const half8*)&Wlg[woff];
    }

  __builtin_amdgcn_wave_barrier();   // wave-local LDS RAW (DS pipe in-order per wave)

  // ---- per-lane j-constants: j = 16*jt + 4*q4 + reg ----
  floatx4 cb4[4], gw4[4];
#pragma unroll
  for (int jt = 0; jt < 4; ++jt) {
    cb4[jt] = *(const floatx4*)(cbg + 16 * jt + 4 * q4);
    gw4[jt] = *(const floatx4*)(gwg + 16 * jt + 4 * q4);
  }
  const float cw = cwsgw[0], sgw = cwsgw[1];

  // ---- phase 2: MFMA K-loops + per-et epilogue ----
#pragma unroll
  for (int et = 0; et < 4; ++et) {
    floatx4 acc0[4], acc1[4];
#pragma unroll
    for (int jt = 0; jt < 4; ++jt) {
      acc0[jt] = (floatx4){0.f, 0.f, 0.f, 0.f};
      acc1[jt] = (floatx4){0.f, 0.f, 0.f, 0.f};
    }
#pragma unroll
    for (int kc = 0; kc < 2; ++kc) {
      const int xoff = wave * 4096 + ((et * 2 + kc) * 4 + q4) * 128 + c15 * 8;
      const half8 xh = *(const half8*)&XHs[xoff];
      const half8 xl = *(const half8*)&XLs[xoff];
#pragma unroll
      for (int jt = 0; jt < 4; ++jt) {
        acc0[jt] = __builtin_amdgcn_mfma_f32_16x16x32_f16(whr[jt][kc], xh, acc0[jt], 0, 0, 0);
        acc1[jt] = __builtin_amdgcn_mfma_f32_16x16x32_f16(whr[jt][kc], xl, acc1[jt], 0, 0, 0);
        acc1[jt] = __builtin_amdgcn_mfma_f32_16x16x32_f16(wlr[jt][kc], xh, acc1[jt], 0, 0, 0);
      }
    }
    // ---- epilogue for edges e2 = 16*et + c15 (t is already centered) ----
    const int e2 = 16 * et + c15;
    const float rse = __shfl(rstd, e2, 64);
    float s1 = 0.f, s2 = 0.f, s3 = 0.f;
#pragma unroll
    for (int jt = 0; jt < 4; ++jt) {
      const floatx4 t4 = acc0[jt] + acc1[jt] * (1.f / 512.f);
#pragma unroll
      for (int rg = 0; rg < 4; ++rg) {
        const float pre = fmaf(rse, t4[rg], cb4[jt][rg]);
        const float tr = fmaxf(pre, 0.f);
        s1 += tr;
        s2 = fmaf(tr, tr, s2);
        s3 = fmaf(tr, gw4[jt][rg], s3);
      }
    }
    // sum over the 4 quads (disjoint 16-j subsets)
    s1 += __shfl_xor(s1, 16, 64); s1 += __shfl_xor(s1, 32, 64);
    s2 += __shfl_xor(s2, 16, 64); s2 += __shfl_xor(s2, 32, 64);
    s3 += __shfl_xor(s3, 16, 64); s3 += __shfl_xor(s3, 32, 64);
    // b/r/c of edge e2 live in lane e2 of this wave
    const int b2 = __shfl(b, e2, 64);
    const int r2 = __shfl(r, e2, 64);
    const int c2 = __shfl(c, e2, 64);
    if (q4 == 0) {
      const float mu2 = s1 * (1.f / FF);
      const float var2 = s2 * (1.f / FF) - mu2 * mu2;
      const float rstd2 = 1.f / sqrtf(var2 + 1e-5f);
      const float logit = fmaf(rstd2, fmaf(-mu2, sgw, s3), cw);
      L[(b2 * NSINK + (r2 - TT)) * NSRC + c2] = logit;
    }
  }
}

// ---------------- argmax over sources + scatter ones ----------------
__global__ __launch_bounds__(256) void argmax_scatter(
    const float* __restrict__ L, const float* __restrict__ gum,
    float* __restrict__ out) {
  const int task = blockIdx.x * 4 + (threadIdx.x >> 6);  // ((s*B+b)*192+row)
  const int lane = threadIdx.x & 63;
  const int row = task % NSINK;
  const int sb = task / NSINK;   // s*B + b
  const int b = sb & 7;
  const int r = row + TT;

  const float* __restrict__ lrow = L + (b * NSINK + row) * NSRC;
  const float* __restrict__ grow = gum + task * NSRC;

  float bv = -INFINITY;
  int bi = 0;
  for (int c = lane; c < r; c += 64) {
    const float v = lrow[c] + grow[c];
    if (v > bv) { bv = v; bi = c; }   // strict > keeps smallest index per lane
  }
#pragma unroll
  for (int off = 32; off > 0; off >>= 1) {
    const float ov = __shfl_xor(bv, off, 64);
    const int oi = __shfl_xor(bi, off, 64);
    if (ov > bv || (ov == bv && oi < bi)) { bv = ov; bi = oi; }
  }
  if (lane == 0) out[(b * NN + r) * NN + bi] = 1.0f;
}

extern "C" void kernel_launch(void* const* d_in, const int* in_sizes, int n_in,
                              void* d_out, int out_size, void* d_ws, size_t ws_size,
                              hipStream_t stream) {
  const float* nodes = (const float*)d_in[0];
  const float* w1 = (const float*)d_in[1];
  const float* b1 = (const float*)d_in[2];
  const float* g1 = (const float*)d_in[3];
  const float* be1 = (const float*)d_in[4];
  const float* w2 = (const float*)d_in[5];
  const float* b2 = (const float*)d_in[6];
  const float* g2 = (const float*)d_in[7];
  const float* be2 = (const float*)d_in[8];
  const float* w3 = (const float*)d_in[9];
  const float* b3 = (const float*)d_in[10];
  const float* gum = (const float*)d_in[11];
  const int* bidx = (const int*)d_in[12];
  const int* ridx = (const int*)d_in[13];
  const int* cidx = (const int*)d_in[14];
  float* out = (float*)d_out;

  // workspace layout (floats)
  float* ws = (float*)d_ws;
  float* A = ws;                       // 8*384*64 = 196608
  float* Bv = A + BN * FF;             // 196608
  unsigned short* Whg = (unsigned short*)(ws + 393216);  // 4096 ushort (8 KB)
  unsigned short* Wlg = Whg + 4096;                      // 4096 ushort -> ends at float 397312
  float* cb = ws + 397312;             // 64
  float* gw = cb + FF;                 // 64
  float* cwsgw = gw + FF;              // 2
  float* L = ws + 397520;              // 8*192*383 = 588288
  (void)ws_size; (void)n_in; (void)in_sizes; (void)out_size;

  hipLaunchKernelGGL(prep_all, dim3(BN / 4 + 1), dim3(64), 0, stream,
                     nodes, w1, b1, w2, b2, g1, be1, g2, be2, w3, b3,
                     A, Bv, Whg, Wlg, cb, gw, cwsgw);
  hipLaunchKernelGGL(edge_mlp, dim3(NBLKE), dim3(128), 0, stream,
                     A, Bv, Whg, Wlg, cb, gw, cwsgw, bidx, ridx, cidx, L,
                     (float4*)out);
  hipLaunchKernelGGL(argmax_scatter, dim3((SS * BB * NSINK) / 4), dim3(256), 0, stream,
                     L, gum, out);
}

// Round 17
// 134.892 us; speedup vs baseline: 1.5917x; 1.5917x over previous
//
#include <hip/hip_runtime.h>
#include <math.h>
#include <stdint.h>

// Problem constants (static per reference)
#define BB 8
#define NN 384
#define FF 64
#define TT 192
#define NSRC 383          // T + TAU - 1
#define NSINK 192
#define SS 5
#define NEDGE 441600      // B * 55200
#define BN (BB * NN)      // 3072
#define TILE_E 256        // edges per block (4 waves x 64, lane <-> edge)
#define NBLKE (NEDGE / TILE_E)    // 1725 exactly
#define OUTV ((BB * NN * NN) / 4) // 294912 float4 to zero

typedef _Float16 half8 __attribute__((ext_vector_type(8)));
typedef __fp16 fp16x2 __attribute__((ext_vector_type(2)));
typedef float floatx4 __attribute__((ext_vector_type(4)));

// 2-limb f16 split (prep side, RNE): x ~= h + l/512
static __device__ __forceinline__ void split_f16(float x, uint16_t& h, uint16_t& l) {
  const _Float16 hh = (_Float16)x;
  const float hb = (float)hh;
  const _Float16 ll = (_Float16)((x - hb) * 512.f);
  h = __builtin_bit_cast(uint16_t, hh);
  l = __builtin_bit_cast(uint16_t, ll);
}

// pair split via v_cvt_pkrtz (RTZ hi; residual captured exactly by the lo limb)
static __device__ __forceinline__ void split_pair(float x0, float x1,
                                                  uint32_t& hi, uint32_t& lo) {
  const fp16x2 h = __builtin_amdgcn_cvt_pkrtz(x0, x1);
  const float hb0 = (float)h.x, hb1 = (float)h.y;
  const fp16x2 l = __builtin_amdgcn_cvt_pkrtz((x0 - hb0) * 512.f, (x1 - hb1) * 512.f);
  hi = __builtin_bit_cast(uint32_t, h);
  lo = __builtin_bit_cast(uint32_t, l);
}

// ---------------- prep: node projections + weight folding + W f16-limb frags ----------------
// W frag slab (A-operand layout, per limb): ushort idx = (((jt*2+kc)*4+q)*16 + m)*8 + jj
//   <-> W[k = 32*kc + 8*q + jj][j = 16*jt + m]   (g1-folded weight)
__global__ __launch_bounds__(64) void prep_all(
    const float* __restrict__ nodes, const float* __restrict__ w1,
    const float* __restrict__ b1,
    const float* __restrict__ w2, const float* __restrict__ b2,
    const float* __restrict__ g1, const float* __restrict__ be1,
    const float* __restrict__ g2, const float* __restrict__ be2,
    const float* __restrict__ w3, const float* __restrict__ b3,
    float* __restrict__ A, float* __restrict__ Bv,
    unsigned short* __restrict__ Whg, unsigned short* __restrict__ Wlg,
    float* __restrict__ wcol, float* __restrict__ cb,
    float* __restrict__ gw, float* __restrict__ cwsgw) {
  const int blk = blockIdx.x;
  const int k = threadIdx.x;
  if (blk < BN / 4) {
    const int bn0 = blk * 4;
    __shared__ float nd[4][FF];
#pragma unroll
    for (int i = 0; i < 4; ++i) nd[i][k] = nodes[(bn0 + i) * FF + k];
    __syncthreads();
    const float bk = b1[k];
    float a0 = bk, a1 = bk, a2 = bk, a3 = bk;
    float q0 = 0.f, q1 = 0.f, q2 = 0.f, q3 = 0.f;
#pragma unroll 8
    for (int f = 0; f < FF; ++f) {
      const float wt = w1[f * FF + k];
      const float wb = w1[(FF + f) * FF + k];
      const float n0 = nd[0][f], n1 = nd[1][f], n2 = nd[2][f], n3 = nd[3][f];
      a0 = fmaf(n0, wt, a0); a1 = fmaf(n1, wt, a1);
      a2 = fmaf(n2, wt, a2); a3 = fmaf(n3, wt, a3);
      q0 = fmaf(n0, wb, q0); q1 = fmaf(n1, wb, q1);
      q2 = fmaf(n2, wb, q2); q3 = fmaf(n3, wb, q3);
    }
    A[(bn0 + 0) * FF + k] = a0;  Bv[(bn0 + 0) * FF + k] = q0;
    A[(bn0 + 1) * FF + k] = a1;  Bv[(bn0 + 1) * FF + k] = q1;
    A[(bn0 + 2) * FF + k] = a2;  Bv[(bn0 + 2) * FF + k] = q2;
    A[(bn0 + 3) * FF + k] = a3;  Bv[(bn0 + 3) * FF + k] = q3;
  } else {
    const int j = k;
    const int jt = j >> 4, m = j & 15;
    float cbj = b2[j];
    float wc = 0.f;
    for (int kk = 0; kk < FF; ++kk) {
      const float wraw = w2[kk * FF + j];
      const float w = g1[kk] * wraw;
      wc += w;
      cbj = fmaf(be1[kk], wraw, cbj);
      uint16_t hu, lu;
      split_f16(w, hu, lu);
      const int kc = kk >> 5, qq = (kk >> 3) & 3, jj = kk & 7;
      const int idx = (((jt * 2 + kc) * 4 + qq) * 16 + m) * 8 + jj;
      Whg[idx] = hu;
      Wlg[idx] = lu;
    }
    wcol[j] = wc;
    cb[j] = cbj;
    const float gwj = g2[j] * w3[j];
    gw[j] = gwj;
    __shared__ float sA[FF], sB[FF];
    sA[j] = gwj;
    sB[j] = be2[j] * w3[j];
    __syncthreads();
    if (j == 0) {
      float a = 0.f, bq = 0.f;
      for (int i = 0; i < FF; ++i) { a += sA[i]; bq += sB[i]; }
      cwsgw[0] = b3[0] + bq;
      cwsgw[1] = a;
    }
  }
}

// ---------------- main: MFMA edge MLP; W frags in registers, X limbs in LDS ----------------
// 256 thr = 4 waves, wave owns 64 edges (local edge = lane).
// mfma_f32_16x16x32_f16: A[m=lane&15][k=8*(lane>>4)+jj]; D col=lane&15, row=4*(lane>>4)+reg.
// NOTE (r16 lesson): this design needs the full 256-VGPR budget -> waves/SIMD must be 2.
__global__ __launch_bounds__(256, 2) void edge_mlp(
    const float* __restrict__ A, const float* __restrict__ Bv,
    const unsigned short* __restrict__ Whg, const unsigned short* __restrict__ Wlg,
    const float* __restrict__ wcolg, const float* __restrict__ cbg,
    const float* __restrict__ gwg, const float* __restrict__ cwsgw,
    const int* __restrict__ bidx, const int* __restrict__ ridx,
    const int* __restrict__ cidx, float* __restrict__ L,
    float4* __restrict__ outv) {
  __shared__ __align__(16) unsigned short XHs[16384];   // 32 KB  X hi frags (4 waves)
  __shared__ __align__(16) unsigned short XLs[16384];   // 32 KB  X lo frags

  const int tid = threadIdx.x;       // 0..255
  const int wave = tid >> 6;
  const int lane = tid & 63;
  const int q4 = lane >> 4;          // quad
  const int c15 = lane & 15;

  // fused zeroing of the output grid
  const int gtid = blockIdx.x * 256 + tid;
  if (gtid < OUTV) outv[gtid] = make_float4(0.f, 0.f, 0.f, 0.f);

  // ---- hoist W frags into registers (16 KB table, L1-hot across blocks) ----
  half8 whr[4][2], wlr[4][2];
#pragma unroll
  for (int jt = 0; jt < 4; ++jt)
#pragma unroll
    for (int kc = 0; kc < 2; ++kc) {
      const int woff = ((jt * 2 + kc) * 4 + q4) * 128 + c15 * 8;
      whr[jt][kc] = *(const half8*)&Whg[woff];
      wlr[jt][kc] = *(const half8*)&Wlg[woff];
    }

  // ---- phase 1: lane <-> edge; gather, relu, stats, pkrtz-split into B-frag layout ----
  const int ge = blockIdx.x * TILE_E + tid;
  const int b = bidx[ge], r = ridx[ge], c = cidx[ge];
  const int et_own = lane >> 4, n_own = lane & 15;
  float mu, rstd;
  {
    const float4* pa = (const float4*)(A + (b * NN + r) * FF);
    const float4* pb = (const float4*)(Bv + (b * NN + c) * FF);
    unsigned short* dh = &XHs[wave * 4096 + n_own * 8];
    unsigned short* dl = &XLs[wave * 4096 + n_own * 8];
    float s = 0.f, q = 0.f;
#pragma unroll
    for (int g = 0; g < 8; ++g) {     // g -> k in [8g, 8g+8): kc=g>>2, q=g&3
      const float4 av0 = pa[2 * g], av1 = pa[2 * g + 1];
      const float4 bv0 = pb[2 * g], bv1 = pb[2 * g + 1];
      const float x0 = fmaxf(av0.x + bv0.x, 0.f);
      const float x1 = fmaxf(av0.y + bv0.y, 0.f);
      const float x2 = fmaxf(av0.z + bv0.z, 0.f);
      const float x3 = fmaxf(av0.w + bv0.w, 0.f);
      const float x4 = fmaxf(av1.x + bv1.x, 0.f);
      const float x5 = fmaxf(av1.y + bv1.y, 0.f);
      const float x6 = fmaxf(av1.z + bv1.z, 0.f);
      const float x7 = fmaxf(av1.w + bv1.w, 0.f);
      s += x0 + x1 + x2 + x3 + x4 + x5 + x6 + x7;
      q = fmaf(x0, x0, q); q = fmaf(x1, x1, q);
      q = fmaf(x2, x2, q); q = fmaf(x3, x3, q);
      q = fmaf(x4, x4, q); q = fmaf(x5, x5, q);
      q = fmaf(x6, x6, q); q = fmaf(x7, x7, q);
      int4 hi4, lo4;
      split_pair(x0, x1, *(uint32_t*)&hi4.x, *(uint32_t*)&lo4.x);
      split_pair(x2, x3, *(uint32_t*)&hi4.y, *(uint32_t*)&lo4.y);
      split_pair(x4, x5, *(uint32_t*)&hi4.z, *(uint32_t*)&lo4.z);
      split_pair(x6, x7, *(uint32_t*)&hi4.w, *(uint32_t*)&lo4.w);
      const int choff = ((et_own * 2 + (g >> 2)) * 4 + (g & 3)) * 128;
      *(int4*)(dh + choff) = hi4;
      *(int4*)(dl + choff) = lo4;
    }
    mu = s * (1.f / FF);
    rstd = 1.f / sqrtf(q * (1.f / FF) - mu * mu + 1e-5f);
  }

  __syncthreads();   // all X slabs visible

  // ---- per-lane j-constants: j = 16*jt + 4*q4 + reg ----
  floatx4 wc4[4], cb4[4], gw4[4];
#pragma unroll
  for (int jt = 0; jt < 4; ++jt) {
    wc4[jt] = *(const floatx4*)(wcolg + 16 * jt + 4 * q4);
    cb4[jt] = *(const floatx4*)(cbg + 16 * jt + 4 * q4);
    gw4[jt] = *(const floatx4*)(gwg + 16 * jt + 4 * q4);
  }
  const float cw = cwsgw[0], sgw = cwsgw[1];

  // ---- phase 2: MFMA K-loops + per-et epilogue ----
#pragma unroll
  for (int et = 0; et < 4; ++et) {
    floatx4 acc0[4], acc1[4];
#pragma unroll
    for (int jt = 0; jt < 4; ++jt) {
      acc0[jt] = (floatx4){0.f, 0.f, 0.f, 0.f};
      acc1[jt] = (floatx4){0.f, 0.f, 0.f, 0.f};
    }
#pragma unroll
    for (int kc = 0; kc < 2; ++kc) {
      const int xoff = wave * 4096 + ((et * 2 + kc) * 4 + q4) * 128 + c15 * 8;
      const half8 xh = *(const half8*)&XHs[xoff];
      const half8 xl = *(const half8*)&XLs[xoff];
#pragma unroll
      for (int jt = 0; jt < 4; ++jt) {
        acc0[jt] = __builtin_amdgcn_mfma_f32_16x16x32_f16(whr[jt][kc], xh, acc0[jt], 0, 0, 0);
        acc1[jt] = __builtin_amdgcn_mfma_f32_16x16x32_f16(whr[jt][kc], xl, acc1[jt], 0, 0, 0);
        acc1[jt] = __builtin_amdgcn_mfma_f32_16x16x32_f16(wlr[jt][kc], xh, acc1[jt], 0, 0, 0);
      }
    }
    // ---- epilogue for edges e2 = 16*et + c15 ----
    const int e2 = 16 * et + c15;
    const float mue = __shfl(mu, e2, 64);
    const float rse = __shfl(rstd, e2, 64);
    float s1 = 0.f, s2 = 0.f, s3 = 0.f;
#pragma unroll
    for (int jt = 0; jt < 4; ++jt) {
      const floatx4 t4 = acc0[jt] + acc1[jt] * (1.f / 512.f);
#pragma unroll
      for (int rg = 0; rg < 4; ++rg) {
        const float pre = fmaf(rse, fmaf(-mue, wc4[jt][rg], t4[rg]), cb4[jt][rg]);
        const float tr = fmaxf(pre, 0.f);
        s1 += tr;
        s2 = fmaf(tr, tr, s2);
        s3 = fmaf(tr, gw4[jt][rg], s3);
      }
    }
    // sum over the 4 quads (disjoint 16-j subsets)
    s1 += __shfl_xor(s1, 16, 64); s1 += __shfl_xor(s1, 32, 64);
    s2 += __shfl_xor(s2, 16, 64); s2 += __shfl_xor(s2, 32, 64);
    s3 += __shfl_xor(s3, 16, 64); s3 += __shfl_xor(s3, 32, 64);
    // b/r/c of edge e2 live in lane e2 of this wave
    const int b2 = __shfl(b, e2, 64);
    const int r2 = __shfl(r, e2, 64);
    const int c2 = __shfl(c, e2, 64);
    if (q4 == 0) {
      const float mu2 = s1 * (1.f / FF);
      const float var2 = s2 * (1.f / FF) - mu2 * mu2;
      const float rstd2 = 1.f / sqrtf(var2 + 1e-5f);
      const float logit = fmaf(rstd2, fmaf(-mu2, sgw, s3), cw);
      L[(b2 * NSINK + (r2 - TT)) * NSRC + c2] = logit;
    }
  }
}

// ---------------- argmax over sources + scatter ones ----------------
__global__ __launch_bounds__(256) void argmax_scatter(
    const float* __restrict__ L, const float* __restrict__ gum,
    float* __restrict__ out) {
  const int task = blockIdx.x * 4 + (threadIdx.x >> 6);  // ((s*B+b)*192+row)
  const int lane = threadIdx.x & 63;
  const int row = task % NSINK;
  const int sb = task / NSINK;   // s*B + b
  const int b = sb & 7;
  const int r = row + TT;

  const float* __restrict__ lrow = L + (b * NSINK + row) * NSRC;
  const float* __restrict__ grow = gum + task * NSRC;

  float bv = -INFINITY;
  int bi = 0;
  for (int c = lane; c < r; c += 64) {
    const float v = lrow[c] + grow[c];
    if (v > bv) { bv = v; bi = c; }   // strict > keeps smallest index per lane
  }
#pragma unroll
  for (int off = 32; off > 0; off >>= 1) {
    const float ov = __shfl_xor(bv, off, 64);
    const int oi = __shfl_xor(bi, off, 64);
    if (ov > bv || (ov == bv && oi < bi)) { bv = ov; bi = oi; }
  }
  if (lane == 0) out[(b * NN + r) * NN + bi] = 1.0f;
}

extern "C" void kernel_launch(void* const* d_in, const int* in_sizes, int n_in,
                              void* d_out, int out_size, void* d_ws, size_t ws_size,
                              hipStream_t stream) {
  const float* nodes = (const float*)d_in[0];
  const float* w1 = (const float*)d_in[1];
  const float* b1 = (const float*)d_in[2];
  const float* g1 = (const float*)d_in[3];
  const float* be1 = (const float*)d_in[4];
  const float* w2 = (const float*)d_in[5];
  const float* b2 = (const float*)d_in[6];
  const float* g2 = (const float*)d_in[7];
  const float* be2 = (const float*)d_in[8];
  const float* w3 = (const float*)d_in[9];
  const float* b3 = (const float*)d_in[10];
  const float* gum = (const float*)d_in[11];
  const int* bidx = (const int*)d_in[12];
  const int* ridx = (const int*)d_in[13];
  const int* cidx = (const int*)d_in[14];
  float* out = (float*)d_out;

  // workspace layout (floats)
  float* ws = (float*)d_ws;
  float* A = ws;                       // 8*384*64 = 196608
  float* Bv = A + BN * FF;             // 196608
  unsigned short* Whg = (unsigned short*)(ws + 393216);  // 4096 ushort (8 KB)
  unsigned short* Wlg = Whg + 4096;                      // 4096 ushort -> ends at float 397312
  float* wcol = ws + 397312;           // 64
  float* cb = wcol + FF;               // 64
  float* gw = cb + FF;                 // 64
  float* cwsgw = gw + FF;              // 2
  float* L = ws + 397520;              // 8*192*383 = 588288
  (void)ws_size; (void)n_in; (void)in_sizes; (void)out_size;

  hipLaunchKernelGGL(prep_all, dim3(BN / 4 + 1), dim3(64), 0, stream,
                     nodes, w1, b1, w2, b2, g1, be1, g2, be2, w3, b3,
                     A, Bv, Whg, Wlg, wcol, cb, gw, cwsgw);
  hipLaunchKernelGGL(edge_mlp, dim3(NBLKE), dim3(256), 0, stream,
                     A, Bv, Whg, Wlg, wcol, cb, gw, cwsgw, bidx, ridx, cidx, L,
                     (float4*)out);
  hipLaunchKernelGGL(argmax_scatter, dim3((SS * BB * NSINK) / 4), dim3(256), 0, stream,
                     L, gum, out);
}